// Round 3
// baseline (146.741 us; speedup 1.0000x reference)
//
#include <hip/hip_runtime.h>

#define B 16
#define N 1024
#define NF 128
#define NL 3
#define AH 64
#define HC 192   // NL*AH
#define FCH 128
#define NC 10
#define L2E 1.44269504088896f

typedef __attribute__((ext_vector_type(8))) short bf16x8;
typedef __attribute__((ext_vector_type(4))) float f32x4;

static __device__ __forceinline__ unsigned short f2bf(float f) {
  unsigned int x = __builtin_bit_cast(unsigned int, f);
  unsigned int r = (x + 0x7fffu + ((x >> 16) & 1u)) >> 16;   // RNE
  return (unsigned short)r;
}

// ---------------------------------------------------------------------------
// Kernel P (fused): even blocks = feat (16 rows: h_t bf16 transposed, f1/f2
// pre-scaled by log2e), odd blocks = adj -> 64-bit bitmask via ballot.
// grid = 2048 blocks x 192 threads.
// ---------------------------------------------------------------------------
__global__ __launch_bounds__(192) void k_prep(
    const float* __restrict__ x, const float* __restrict__ adj,
    const float* __restrict__ Ws, const float* __restrict__ a1,
    const float* __restrict__ a2, unsigned short* __restrict__ h_t,
    float* __restrict__ f1, float* __restrict__ f2,
    unsigned long long* __restrict__ msk)
{
  const int bid = blockIdx.x, t = threadIdx.x;

  if (bid & 1) {                           // ---- mask role ----
    const int lane = t & 63;
    unsigned int c = (unsigned)((bid >> 1) * 3 + (t >> 6));
    for (; c < (unsigned)(B * N * (N / 64)); c += 1024 * 3) {
      const float v = adj[((size_t)c << 6) + lane];
      const unsigned long long bal = __ballot(v > 0.f);
      if (lane == 0) msk[c] = bal;
    }
    return;
  }

  // ---- feat role: rows n0..n0+15 ----
  __shared__ float xs[16][NF];
  const int n0 = (bid >> 1) * 16;
  const int gb = n0 >> 10, nl0 = n0 & 1023;

  for (int p = t; p < 16 * NF / 4; p += 192) {
    const int row = p >> 5, c4 = p & 31;
    *(float4*)&xs[row][c4 * 4] =
        *(const float4*)&x[(size_t)(n0 + row) * NF + c4 * 4];
  }
  __syncthreads();

  const int l = t >> 6, k = t & 63;
  const float* w = Ws + (size_t)l * NF * AH + k;   // stride AH per feature

  float acc[16];
  #pragma unroll
  for (int ii = 0; ii < 16; ++ii) acc[ii] = 0.f;

  for (int f0 = 0; f0 < NF; f0 += 4) {
    const float w0 = w[(f0 + 0) * AH], w1 = w[(f0 + 1) * AH];
    const float w2 = w[(f0 + 2) * AH], w3 = w[(f0 + 3) * AH];
    #pragma unroll
    for (int ii = 0; ii < 16; ++ii) {
      const float4 xv = *(const float4*)&xs[ii][f0];
      acc[ii] += xv.x * w0 + xv.y * w1 + xv.z * w2 + xv.w * w3;
    }
  }

  // h_t store: 16 consecutive bf16 per thread (32B)
  unsigned short* dst = h_t + (((size_t)(gb * HC + t)) << 10) + nl0;
  #pragma unroll
  for (int g8 = 0; g8 < 2; ++g8) {
    uint4 vv;
    unsigned int* vp = (unsigned int*)&vv;
    #pragma unroll
    for (int jj = 0; jj < 4; ++jj) {
      const int ii = g8 * 8 + jj * 2;
      vp[jj] = (unsigned int)f2bf(acc[ii]) | ((unsigned int)f2bf(acc[ii + 1]) << 16);
    }
    *(uint4*)&dst[g8 * 8] = vv;
  }

  // f1/f2 (pre-scaled by log2 e)
  const float a1v = a1[t] * L2E, a2v = a2[t] * L2E;
  #pragma unroll
  for (int ii = 0; ii < 16; ++ii) {
    float p1 = acc[ii] * a1v, p2 = acc[ii] * a2v;
    #pragma unroll
    for (int off = 32; off; off >>= 1) {
      p1 += __shfl_down(p1, off);
      p2 += __shfl_down(p2, off);
    }
    if (k == 0) {
      f1[(size_t)l * (B * N) + n0 + ii] = p1;
      f2[(size_t)l * (B * N) + n0 + ii] = p2;
    }
  }
}

// ---------------------------------------------------------------------------
// Kernel B: fused 3-layer GAT attention + MFMA PV + relu + pool.
// grid = B*(N/16) = 1024 blocks, 192 threads = 3 waves (one per layer).
// Wave owns 16 complete output rows: no cross-wave reduction, no LDS tiles,
// no barriers in the j-loop. adj arrives as bitmask words.
// ---------------------------------------------------------------------------
__global__ __launch_bounds__(192) void k_att(
    const unsigned int* __restrict__ msk, const unsigned short* __restrict__ h_t,
    const float* __restrict__ f1, const float* __restrict__ f2,
    float* __restrict__ pooled)
{
  const int blk = blockIdx.x;
  const int b = blk >> 6;                 // 64 i-blocks per batch
  const int i0 = (blk & 63) * 16;
  const int t = threadIdx.x;
  const int l = t >> 6, lane = t & 63;
  const int lr = lane & 15, lg = lane >> 4;

  // per-block softmax shift: m = max_j f2[l][b][j] (shift cancels exactly)
  __shared__ float msh[NL];
  {
    const float* p = f2 + (size_t)l * (B * N) + b * N;
    float v = -1e30f;
    for (int i = lane; i < N; i += 64) v = fmaxf(v, p[i]);
    #pragma unroll
    for (int off = 32; off; off >>= 1) v = fmaxf(v, __shfl_down(v, off));
    if (lane == 0) msh[l] = v;
  }
  __syncthreads();
  const float mval = msh[l];

  const float f1r = f1[(size_t)l * (B * N) + b * N + i0 + lr];
  const float tts = f1r + mval;
  const float sr = fmaxf(tts, 0.f) + 0.2f * fminf(tts, 0.f);  // upper bound (scaled domain)

  const unsigned int* mrow = msk + ((size_t)(b * N + i0 + lr)) * 32;  // 32 words/row
  const unsigned short* hb = h_t + (((size_t)(b * HC + l * 64)) << 10);
  const float* f2p = f2 + (size_t)l * (B * N) + b * N;
  const int klane = lg * 8;

  f32x4 acc[4];
  #pragma unroll
  for (int n = 0; n < 4; ++n) acc[n] = (f32x4){0.f, 0.f, 0.f, 0.f};
  float rs = 0.f;

  for (int j0 = 0; j0 < N; j0 += 64) {
    const uint2 mw = *(const uint2*)&mrow[j0 >> 5];

    bf16x8 bfr[2][4];
    #pragma unroll
    for (int ks = 0; ks < 2; ++ks)
      #pragma unroll
      for (int n = 0; n < 4; ++n)
        bfr[ks][n] = *(const bf16x8*)&hb[(((size_t)(n * 16 + lr)) << 10) + j0 + ks * 32 + klane];

    #pragma unroll
    for (int ks = 0; ks < 2; ++ks) {
      const float4 q0 = *(const float4*)&f2p[j0 + ks * 32 + klane];
      const float4 q1 = *(const float4*)&f2p[j0 + ks * 32 + klane + 4];
      const float fv[8] = {q0.x, q0.y, q0.z, q0.w, q1.x, q1.y, q1.z, q1.w};
      const unsigned int wbits = (ks ? mw.y : mw.x) >> klane;

      bf16x8 av;
      float s8 = 0.f;
      #pragma unroll
      for (int e = 0; e < 8; ++e) {
        const float tt = f1r + fv[e];
        const float el = fmaxf(tt, 0.f) + 0.2f * fminf(tt, 0.f);
        float pv = exp2f(el - sr);                 // el<=sr: in (0,1]
        pv = ((wbits >> e) & 1u) ? pv : 0.f;
        s8 += pv;
        av[e] = (short)f2bf(pv);
      }
      rs += s8;

      #pragma unroll
      for (int n = 0; n < 4; ++n)
        acc[n] = __builtin_amdgcn_mfma_f32_16x16x32_bf16(av, bfr[ks][n], acc[n], 0, 0, 0);
    }
  }

  // ---- epilogue (wave-local) ----
  float dnm = rs;
  dnm += __shfl_xor(dnm, 16);
  dnm += __shfl_xor(dnm, 32);               // all lanes: denom(row lr)
  float dn[4];
  #pragma unroll
  for (int r = 0; r < 4; ++r)
    dn[r] = 1.f / fmaxf(__shfl(dnm, lg * 4 + r), 1e-37f);   // denom(row lg*4+r)

  #pragma unroll
  for (int n = 0; n < 4; ++n) {
    float csum = 0.f;
    #pragma unroll
    for (int r = 0; r < 4; ++r) csum += fmaxf(acc[n][r] * dn[r], 0.f);
    csum += __shfl_xor(csum, 16);
    csum += __shfl_xor(csum, 32);
    if (lg == 0) atomicAdd(&pooled[b * HC + l * 64 + n * 16 + lr], csum);
  }
}

// ---------------------------------------------------------------------------
// Kernel C: mean (pooled sums / N) + FC1(relu) + FC2 + softmax.  grid = B.
// ---------------------------------------------------------------------------
__global__ __launch_bounds__(192) void k_head(
    const float* __restrict__ pooled_sums, const float* __restrict__ W1,
    const float* __restrict__ b1, const float* __restrict__ W2,
    const float* __restrict__ b2, float* __restrict__ out)
{
  const int b = blockIdx.x, t = threadIdx.x;
  __shared__ float pooled[HC];
  __shared__ float z[FCH];
  __shared__ float logits[NC];

  if (t < HC) pooled[t] = pooled_sums[b * HC + t] * (1.f / (float)N);
  __syncthreads();

  if (t < FCH) {
    float a = b1[t];
    #pragma unroll 4
    for (int f = 0; f < HC; ++f) a += pooled[f] * W1[(size_t)f * FCH + t];
    z[t] = a > 0.f ? a : 0.f;
  }
  __syncthreads();

  if (t < NC) {
    float a = b2[t];
    #pragma unroll 4
    for (int f = 0; f < FCH; ++f) a += z[f] * W2[(size_t)f * NC + t];
    logits[t] = a;
  }
  __syncthreads();

  if (t == 0) {
    float mx = logits[0];
    for (int c = 1; c < NC; ++c) mx = fmaxf(mx, logits[c]);
    float e[NC], sum = 0.f;
    for (int c = 0; c < NC; ++c) { e[c] = __expf(logits[c] - mx); sum += e[c]; }
    const float inv = 1.f / sum;
    for (int c = 0; c < NC; ++c) out[b * NC + c] = e[c] * inv;
  }
}

// ---------------------------------------------------------------------------
extern "C" void kernel_launch(void* const* d_in, const int* in_sizes, int n_in,
                              void* d_out, int out_size, void* d_ws, size_t ws_size,
                              hipStream_t stream)
{
  const float* x   = (const float*)d_in[0];
  const float* adj = (const float*)d_in[1];
  const float* Ws  = (const float*)d_in[2];
  const float* a1  = (const float*)d_in[3];
  const float* a2  = (const float*)d_in[4];
  const float* W1  = (const float*)d_in[5];
  const float* b1  = (const float*)d_in[6];
  const float* W2  = (const float*)d_in[7];
  const float* b2  = (const float*)d_in[8];
  float* out = (float*)d_out;

  unsigned short* h_t = (unsigned short*)d_ws;                    // B*HC*N bf16
  float* f1   = (float*)(h_t + (size_t)B * HC * N);               // NL*B*N
  float* f2   = f1 + (size_t)NL * B * N;                          // NL*B*N
  float* pooled = f2 + (size_t)NL * B * N;                        // B*HC
  unsigned long long* msk =
      (unsigned long long*)(pooled + (size_t)B * HC + 64);        // B*N*(N/64)

  hipMemsetAsync(pooled, 0, (size_t)B * HC * sizeof(float), stream);
  k_prep<<<2048, 192, 0, stream>>>(x, adj, Ws, a1, a2, h_t, f1, f2, msk);
  k_att <<<B * (N / 16), 192, 0, stream>>>((const unsigned int*)msk, h_t, f1, f2, pooled);
  k_head<<<B, 192, 0, stream>>>(pooled, W1, b1, W2, b2, out);
}

// Round 5
// 99.097 us; speedup vs baseline: 1.4808x; 1.4808x over previous
//
#include <hip/hip_runtime.h>

#define B 16
#define N 1024
#define NF 128
#define NL 3
#define AH 64
#define HC 192   // NL*AH
#define FCH 128
#define NC 10
#define L2E 1.44269504088896f

typedef __attribute__((ext_vector_type(8))) short bf16x8;
typedef __attribute__((ext_vector_type(4))) float f32x4;
typedef __attribute__((ext_vector_type(4))) unsigned int u32x4;

static __device__ __forceinline__ unsigned short f2bf(float f) {
  unsigned int x = __builtin_bit_cast(unsigned int, f);
  return (unsigned short)((x + 0x7fffu + ((x >> 16) & 1u)) >> 16);   // RNE
}
static __device__ __forceinline__ float bf2f(unsigned short u) {
  unsigned int x = ((unsigned int)u) << 16;
  return __builtin_bit_cast(float, x);
}

// ---------------------------------------------------------------------------
// k_wt: Wt_hi/lo[col=192][k=128] bf16 split of Ws[l][f][h]; also zero pooled.
// ---------------------------------------------------------------------------
__global__ __launch_bounds__(256) void k_wt(
    const float* __restrict__ Ws, unsigned short* __restrict__ wt_hi,
    unsigned short* __restrict__ wt_lo, float* __restrict__ pooled)
{
  const int idx = blockIdx.x * 256 + threadIdx.x;     // 96*256 = 24576
  const int col = idx >> 7, k = idx & 127;
  const float w = Ws[(size_t)((col >> 6) * NF + k) * AH + (col & 63)];
  const unsigned short hi = f2bf(w);
  wt_hi[idx] = hi;
  wt_lo[idx] = f2bf(w - bf2f(hi));
  if (idx < B * HC) pooled[idx] = 0.f;
}

// ---------------------------------------------------------------------------
// k_fm: even blocks = feat (64 rows, split-bf16 MFMA GEMM -> h_t bf16
// transposed + f1/f2 in f32, pre-scaled by log2e); odd blocks = adj bitmask.
// grid = 512 blocks x 256 threads.
// ---------------------------------------------------------------------------
__global__ __launch_bounds__(256) void k_fm(
    const float* __restrict__ x, const float* __restrict__ adj,
    const unsigned short* __restrict__ wt_hi, const unsigned short* __restrict__ wt_lo,
    const float* __restrict__ a1, const float* __restrict__ a2,
    unsigned short* __restrict__ h_t, float* __restrict__ f1g,
    float* __restrict__ f2g, unsigned short* __restrict__ msk)
{
  const int bid = blockIdx.x, t = threadIdx.x;

  if (bid & 1) {                          // ---- mask role: 64 adj rows ----
    const int wv = t >> 6, lane = t & 63;
    const int r0 = (bid >> 1) * 64 + wv * 16;
    #pragma unroll 2
    for (int rr = 0; rr < 16; ++rr) {
      const int row = r0 + rr;
      const float* ap = adj + ((size_t)row << 10) + lane * 16;
      unsigned int bits = 0;
      #pragma unroll
      for (int q = 0; q < 4; ++q) {
        const uint4 u = *(const uint4*)(ap + q * 4);
        // adj is exactly 0.0f (0x0) or 1.0f (0x3F800000): nonzero test.
        bits |= (u.x ? 1u : 0u) << (q * 4 + 0);
        bits |= (u.y ? 1u : 0u) << (q * 4 + 1);
        bits |= (u.z ? 1u : 0u) << (q * 4 + 2);
        bits |= (u.w ? 1u : 0u) << (q * 4 + 3);
      }
      msk[((size_t)row << 6) + lane] = (unsigned short)bits;
    }
    return;
  }

  // ---- feat role ----
  __shared__ unsigned short wlds[2][HC][40];   // hi/lo k-slab, 16B-aligned cols
  __shared__ unsigned short hlds[HC][72];      // transpose buffer
  const int fid = bid >> 1;
  const int n0g = fid * 64;                    // global row base
  const int gb = n0g >> 10, nl0 = n0g & 1023;
  const int wv = t >> 6, lane = t & 63;
  const int lr = lane & 15, lg = lane >> 4;
  const int row = n0g + wv * 16 + lr;          // this lane's A row

  f32x4 acc[12];
  #pragma unroll
  for (int n = 0; n < 12; ++n) acc[n] = (f32x4){0.f, 0.f, 0.f, 0.f};

  for (int k0 = 0; k0 < NF; k0 += 32) {
    __syncthreads();                           // prior slab reads done
    for (int p = t; p < HC * 4; p += 256) {    // 768 chunks of 8 ushorts
      const int col = p >> 2, kc = (p & 3) * 8;
      *(uint4*)&wlds[0][col][kc] = *(const uint4*)&wt_hi[col * NF + k0 + kc];
      *(uint4*)&wlds[1][col][kc] = *(const uint4*)&wt_lo[col * NF + k0 + kc];
    }
    __syncthreads();

    const float4 q0 = *(const float4*)&x[(size_t)row * NF + k0 + lg * 8];
    const float4 q1 = *(const float4*)&x[(size_t)row * NF + k0 + lg * 8 + 4];
    const float xv[8] = {q0.x, q0.y, q0.z, q0.w, q1.x, q1.y, q1.z, q1.w};
    bf16x8 xhi, xlo;
    #pragma unroll
    for (int e = 0; e < 8; ++e) {
      const unsigned short hi = f2bf(xv[e]);
      xhi[e] = (short)hi;
      xlo[e] = (short)f2bf(xv[e] - bf2f(hi));
    }
    #pragma unroll
    for (int n = 0; n < 12; ++n) {
      const int col = n * 16 + lr;
      const bf16x8 whi = *(const bf16x8*)&wlds[0][col][lg * 8];
      const bf16x8 wlo = *(const bf16x8*)&wlds[1][col][lg * 8];
      acc[n] = __builtin_amdgcn_mfma_f32_16x16x32_bf16(xhi, whi, acc[n], 0, 0, 0);
      acc[n] = __builtin_amdgcn_mfma_f32_16x16x32_bf16(xhi, wlo, acc[n], 0, 0, 0);
      acc[n] = __builtin_amdgcn_mfma_f32_16x16x32_bf16(xlo, whi, acc[n], 0, 0, 0);
    }
  }

  // f1/f2 (exact f32 from acc), pre-scaled by log2e
  float s1[3][4], s2[3][4];
  #pragma unroll
  for (int l = 0; l < 3; ++l)
    #pragma unroll
    for (int r = 0; r < 4; ++r) { s1[l][r] = 0.f; s2[l][r] = 0.f; }
  #pragma unroll
  for (int n = 0; n < 12; ++n) {
    const int col = n * 16 + lr;
    const float a1v = a1[col] * L2E, a2v = a2[col] * L2E;
    const int l = n >> 2;
    #pragma unroll
    for (int r = 0; r < 4; ++r) {
      s1[l][r] += acc[n][r] * a1v;
      s2[l][r] += acc[n][r] * a2v;
    }
  }
  #pragma unroll
  for (int off = 1; off < 16; off <<= 1)
    #pragma unroll
    for (int l = 0; l < 3; ++l)
      #pragma unroll
      for (int r = 0; r < 4; ++r) {
        s1[l][r] += __shfl_xor(s1[l][r], off);
        s2[l][r] += __shfl_xor(s2[l][r], off);
      }
  if (lr == 0) {
    #pragma unroll
    for (int l = 0; l < 3; ++l)
      #pragma unroll
      for (int r = 0; r < 4; ++r) {
        const int rw = n0g + wv * 16 + lg * 4 + r;
        f1g[(size_t)l * (B * N) + rw] = s1[l][r];
        f2g[(size_t)l * (B * N) + rw] = s2[l][r];
      }
  }

  // h_t: pack bf16 + LDS transpose + coalesced store
  #pragma unroll
  for (int n = 0; n < 12; ++n) {
    const int col = n * 16 + lr;
    #pragma unroll
    for (int rp = 0; rp < 2; ++rp) {
      const unsigned int pr = (unsigned int)f2bf(acc[n][rp * 2]) |
                              ((unsigned int)f2bf(acc[n][rp * 2 + 1]) << 16);
      *(unsigned int*)&hlds[col][wv * 16 + lg * 4 + rp * 2] = pr;
    }
  }
  __syncthreads();
  #pragma unroll
  for (int pass = 0; pass < 6; ++pass) {
    const int col = pass * 32 + (t >> 3);
    const int r8 = (t & 7) * 8;
    *(uint4*)&h_t[(((size_t)(gb * HC + col)) << 10) + nl0 + r8] =
        *(const uint4*)&hlds[col][r8];
  }
}

// ---------------------------------------------------------------------------
// k_att: fused 3-layer GAT attention + MFMA PV + ones-column denominator +
// relu + pool. No exp in the j-loop (separable u/v tables). grid = B*64,
// 192 threads = 3 waves (one per layer), wave owns 16 complete rows.
// ---------------------------------------------------------------------------
__global__ __launch_bounds__(192, 3) void k_att(
    const unsigned char* __restrict__ msk8, const unsigned short* __restrict__ h_t,
    const float* __restrict__ f1, const float* __restrict__ f2,
    float* __restrict__ pooled)
{
  const int blk = blockIdx.x;
  const int b = blk >> 6;
  const int i0 = (blk & 63) * 16;
  const int t = threadIdx.x;
  const int l = t >> 6, lane = t & 63;
  const int lr = lane & 15, lg = lane >> 4;

  __shared__ float uvt[NL][2][N];              // 24 KB u/v tables

  // prologue: layer-l tables + max (built/read only by wave l)
  const float* f2p = f2 + (size_t)l * (B * N) + b * N;
  const int jb = lane * 16;
  float fv[16];
  {
    const float4 c0 = *(const float4*)&f2p[jb];
    const float4 c1 = *(const float4*)&f2p[jb + 4];
    const float4 c2 = *(const float4*)&f2p[jb + 8];
    const float4 c3 = *(const float4*)&f2p[jb + 12];
    fv[0]=c0.x; fv[1]=c0.y; fv[2]=c0.z; fv[3]=c0.w;
    fv[4]=c1.x; fv[5]=c1.y; fv[6]=c1.z; fv[7]=c1.w;
    fv[8]=c2.x; fv[9]=c2.y; fv[10]=c2.z; fv[11]=c2.w;
    fv[12]=c3.x; fv[13]=c3.y; fv[14]=c3.z; fv[15]=c3.w;
  }
  float mx = fv[0];
  #pragma unroll
  for (int e = 1; e < 16; ++e) mx = fmaxf(mx, fv[e]);
  #pragma unroll
  for (int off = 1; off < 64; off <<= 1) mx = fmaxf(mx, __shfl_xor(mx, off));

  {
    float ue[16], ve[16];
    #pragma unroll
    for (int e = 0; e < 16; ++e) {
      ue[e] = exp2f(fv[e]);
      ve[e] = exp2f(0.2f * fv[e]);
    }
    #pragma unroll
    for (int q = 0; q < 4; ++q) {
      *(float4*)&uvt[l][0][jb + q * 4] = (float4){ue[q*4], ue[q*4+1], ue[q*4+2], ue[q*4+3]};
      *(float4*)&uvt[l][1][jb + q * 4] = (float4){ve[q*4], ve[q*4+1], ve[q*4+2], ve[q*4+3]};
    }
  }
  __syncthreads();

  const float f1r = f1[(size_t)l * (B * N) + b * N + i0 + lr];
  const float tts = f1r + mx;
  const float sr = fmaxf(tts, 0.f) + 0.2f * fminf(tts, 0.f);  // valid upper bound
  const float A = exp2f(f1r - sr);
  const float C = exp2f(0.2f * f1r - sr);
  const float T = exp2f(-f1r);                 // u_j > T  <=>  f1+f2 > 0

  const unsigned char* mrow = msk8 + ((size_t)(b * N + i0 + lr) << 7);
  const unsigned short* hb = h_t + (((size_t)(b * HC + l * 64)) << 10);
  const int klane = lg * 8;
  const float* ut = &uvt[l][0][0];
  const float* vt = &uvt[l][1][0];
  const bf16x8 ones = {(short)0x3F80, (short)0x3F80, (short)0x3F80, (short)0x3F80,
                       (short)0x3F80, (short)0x3F80, (short)0x3F80, (short)0x3F80};

  f32x4 acc[4];
  #pragma unroll
  for (int n = 0; n < 4; ++n) acc[n] = (f32x4){0.f, 0.f, 0.f, 0.f};
  f32x4 accd = (f32x4){0.f, 0.f, 0.f, 0.f};

  for (int j0 = 0; j0 < N; j0 += 64) {
    const unsigned long long mw = *(const unsigned long long*)&mrow[j0 >> 3];
    bf16x8 bfr[2][4];
    #pragma unroll
    for (int ks = 0; ks < 2; ++ks)
      #pragma unroll
      for (int n = 0; n < 4; ++n)
        bfr[ks][n] = *(const bf16x8*)&hb[(((size_t)(n * 16 + lr)) << 10) + j0 + ks * 32 + klane];

    #pragma unroll
    for (int ks = 0; ks < 2; ++ks) {
      const int kb = j0 + ks * 32 + klane;
      const float4 u0 = *(const float4*)&ut[kb];
      const float4 u1 = *(const float4*)&ut[kb + 4];
      const float4 v0 = *(const float4*)&vt[kb];
      const float4 v1 = *(const float4*)&vt[kb + 4];
      const float uu[8] = {u0.x, u0.y, u0.z, u0.w, u1.x, u1.y, u1.z, u1.w};
      const float vv[8] = {v0.x, v0.y, v0.z, v0.w, v1.x, v1.y, v1.z, v1.w};
      const unsigned int wb = (unsigned int)(mw >> (ks * 32 + klane));

      unsigned int pk[4];
      #pragma unroll
      for (int ep = 0; ep < 4; ++ep) {
        unsigned int pr[2];
        #pragma unroll
        for (int h = 0; h < 2; ++h) {
          const int e = ep * 2 + h;
          const bool pos = uu[e] > T;
          const float z = pos ? uu[e] : vv[e];
          const float wgt = pos ? A : C;
          float p = wgt * z;
          p = ((wb >> e) & 1u) ? p : 0.f;
          pr[h] = __builtin_bit_cast(unsigned int, p) + 0x8000u;  // round-to-nearest bf16
        }
        pk[ep] = __builtin_amdgcn_perm(pr[1], pr[0], 0x07060302u);
      }
      const u32x4 pkv = {pk[0], pk[1], pk[2], pk[3]};
      const bf16x8 av = __builtin_bit_cast(bf16x8, pkv);

      #pragma unroll
      for (int n = 0; n < 4; ++n)
        acc[n] = __builtin_amdgcn_mfma_f32_16x16x32_bf16(av, bfr[ks][n], acc[n], 0, 0, 0);
      accd = __builtin_amdgcn_mfma_f32_16x16x32_bf16(av, ones, accd, 0, 0, 0);
    }
  }

  // epilogue: rows lg*4+r owned by this lane's acc regs; denom from accd
  float dn[4];
  #pragma unroll
  for (int r = 0; r < 4; ++r) dn[r] = 1.f / fmaxf(accd[r], 1e-37f);

  #pragma unroll
  for (int n = 0; n < 4; ++n) {
    float csum = 0.f;
    #pragma unroll
    for (int r = 0; r < 4; ++r) csum += fmaxf(acc[n][r] * dn[r], 0.f);
    csum += __shfl_xor(csum, 16);
    csum += __shfl_xor(csum, 32);
    if (lg == 0) atomicAdd(&pooled[b * HC + l * 64 + n * 16 + lr], csum);
  }
}

// ---------------------------------------------------------------------------
// k_head: mean + FC1(relu) + FC2 + softmax.  grid = B.
// ---------------------------------------------------------------------------
__global__ __launch_bounds__(192) void k_head(
    const float* __restrict__ pooled_sums, const float* __restrict__ W1,
    const float* __restrict__ b1, const float* __restrict__ W2,
    const float* __restrict__ b2, float* __restrict__ out)
{
  const int b = blockIdx.x, t = threadIdx.x;
  __shared__ float pooled[HC];
  __shared__ float z[FCH];
  __shared__ float logits[NC];

  if (t < HC) pooled[t] = pooled_sums[b * HC + t] * (1.f / (float)N);
  __syncthreads();

  if (t < FCH) {
    float a = b1[t];
    #pragma unroll 4
    for (int f = 0; f < HC; ++f) a += pooled[f] * W1[(size_t)f * FCH + t];
    z[t] = a > 0.f ? a : 0.f;
  }
  __syncthreads();

  if (t < NC) {
    float a = b2[t];
    #pragma unroll 4
    for (int f = 0; f < FCH; ++f) a += z[f] * W2[(size_t)f * NC + t];
    logits[t] = a;
  }
  __syncthreads();

  if (t == 0) {
    float mxl = logits[0];
    for (int c = 1; c < NC; ++c) mxl = fmaxf(mxl, logits[c]);
    float e[NC], sum = 0.f;
    for (int c = 0; c < NC; ++c) { e[c] = __expf(logits[c] - mxl); sum += e[c]; }
    const float inv = 1.f / sum;
    for (int c = 0; c < NC; ++c) out[b * NC + c] = e[c] * inv;
  }
}

// ---------------------------------------------------------------------------
extern "C" void kernel_launch(void* const* d_in, const int* in_sizes, int n_in,
                              void* d_out, int out_size, void* d_ws, size_t ws_size,
                              hipStream_t stream)
{
  const float* x   = (const float*)d_in[0];
  const float* adj = (const float*)d_in[1];
  const float* Ws  = (const float*)d_in[2];
  const float* a1  = (const float*)d_in[3];
  const float* a2  = (const float*)d_in[4];
  const float* W1  = (const float*)d_in[5];
  const float* b1  = (const float*)d_in[6];
  const float* W2  = (const float*)d_in[7];
  const float* b2  = (const float*)d_in[8];
  float* out = (float*)d_out;

  // workspace layout (16B aligned chunks)
  unsigned short* h_t   = (unsigned short*)d_ws;                       // 6.29 MB
  float*          f1    = (float*)(h_t + (size_t)B * HC * N);          // 196 KB
  float*          f2    = f1 + (size_t)NL * B * N;                     // 196 KB
  float*          pooled= f2 + (size_t)NL * B * N;                     // 12 KB
  unsigned short* wt_hi = (unsigned short*)(pooled + B * HC);          // 48 KB
  unsigned short* wt_lo = wt_hi + (size_t)HC * NF;                     // 48 KB
  unsigned short* msk   = wt_lo + (size_t)HC * NF;                     // 2 MB

  k_wt  <<<96,  256, 0, stream>>>(Ws, wt_hi, wt_lo, pooled);
  k_fm  <<<512, 256, 0, stream>>>(x, adj, wt_hi, wt_lo, a1, a2, h_t, f1, f2, msk);
  k_att <<<B * 64, 192, 0, stream>>>((const unsigned char*)msk, h_t, f1, f2, pooled);
  k_head<<<B, 192, 0, stream>>>(pooled, W1, b1, W2, b2, out);
}